// Round 9
// baseline (1477.872 us; speedup 1.0000x reference)
//
#include <hip/hip_runtime.h>

#define NN 50000
#define NE 1600000
#define HID 128
#define NB 196      // dst buckets: dst>>8 -> 0..195 (256 nodes each)
#define BCAP 12288  // per-bucket LDS edge capacity
#define NTILES 782  // ceil(NN/64)

typedef _Float16 half8 __attribute__((ext_vector_type(8)));
typedef float floatx4 __attribute__((ext_vector_type(4)));

// ---------------- CSR build: two-level bucket sort (R5-verified) ----------------

__global__ __launch_bounds__(256) void kb_count(const int* __restrict__ dst,
                                                int* __restrict__ gcnt, int E) {
  __shared__ int cnt[NB];
  int tid = threadIdx.x;
  for (int i = tid; i < NB; i += 256) cnt[i] = 0;
  __syncthreads();
  int base = blockIdx.x * 4096;
  for (int i = 0; i < 16; ++i) {
    int e = base + i * 256 + tid;
    if (e < E) atomicAdd(&cnt[dst[e] >> 8], 1);
  }
  __syncthreads();
  for (int i = tid; i < NB; i += 256)
    if (cnt[i]) atomicAdd(&gcnt[i], cnt[i]);
}

__global__ __launch_bounds__(256) void kb_basescan(const int* __restrict__ gcnt,
                                                   int* __restrict__ bbase,
                                                   int* __restrict__ bcur) {
  __shared__ int s[256];
  int tid = threadIdx.x;
  int v = (tid < NB) ? gcnt[tid] : 0;
  s[tid] = v;
  __syncthreads();
  for (int d = 1; d < 256; d <<= 1) {
    int t = (tid >= d) ? s[tid - d] : 0;
    __syncthreads();
    s[tid] += t;
    __syncthreads();
  }
  int incl = s[tid];
  if (tid < NB) {
    bbase[tid] = incl - v;
    bcur[tid] = incl - v;
  }
  if (tid == NB - 1) bbase[NB] = incl;
}

__global__ __launch_bounds__(256) void kb_partition(const int* __restrict__ src,
                                                    const int* __restrict__ dst,
                                                    int* __restrict__ bcur,
                                                    int2* __restrict__ ebuf, int E) {
  __shared__ int cnt[NB];
  __shared__ int sbase[NB];
  int tid = threadIdx.x;
  for (int i = tid; i < NB; i += 256) cnt[i] = 0;
  __syncthreads();
  int base = blockIdx.x * 4096;
  int myd[16], mys[16];
#pragma unroll
  for (int i = 0; i < 16; ++i) {
    int e = base + i * 256 + tid;
    if (e < E) {
      myd[i] = dst[e];
      mys[i] = src[e];
      atomicAdd(&cnt[myd[i] >> 8], 1);
    } else {
      myd[i] = -1;
    }
  }
  __syncthreads();
  for (int i = tid; i < NB; i += 256)
    sbase[i] = cnt[i] ? atomicAdd(&bcur[i], cnt[i]) : 0;
  __syncthreads();
  for (int i = tid; i < NB; i += 256) cnt[i] = 0;
  __syncthreads();
#pragma unroll
  for (int i = 0; i < 16; ++i) {
    if (myd[i] >= 0) {
      int b = myd[i] >> 8;
      int r = atomicAdd(&cnt[b], 1);
      ebuf[sbase[b] + r] = make_int2(mys[i], myd[i]);
    }
  }
}

__global__ __launch_bounds__(256) void kb_csr(const int2* __restrict__ ebuf,
                                              const int* __restrict__ bbase,
                                              int* __restrict__ rs,
                                              int* __restrict__ eidx, int M) {
  __shared__ int cnt[256];
  __shared__ int off[256];
  __shared__ int sbuf[BCAP];
  int tid = threadIdx.x;
  int b = blockIdx.x;
  int lo = bbase[b], hi = bbase[b + 1];
  int n = hi - lo;
  cnt[tid] = 0;
  __syncthreads();
  for (int i = tid; i < n; i += 256) atomicAdd(&cnt[ebuf[lo + i].y & 255], 1);
  __syncthreads();
  int v = cnt[tid];
  off[tid] = v;
  __syncthreads();
  for (int d = 1; d < 256; d <<= 1) {
    int t = (tid >= d) ? off[tid - d] : 0;
    __syncthreads();
    off[tid] += t;
    __syncthreads();
  }
  int excl = off[tid] - v;
  int gnode = b * 256 + tid;
  if (gnode < M) rs[gnode] = lo + excl;
  if (b == NB - 1 && tid == 0) rs[M] = bbase[NB];
  __syncthreads();
  cnt[tid] = excl;
  __syncthreads();
  if (n <= BCAP) {
    for (int i = tid; i < n; i += 256) {
      int2 ed = ebuf[lo + i];
      int r = atomicAdd(&cnt[ed.y & 255], 1);
      sbuf[r] = ed.x;
    }
    __syncthreads();
    for (int i = tid; i < n; i += 256) eidx[lo + i] = sbuf[i];
  } else {
    for (int i = tid; i < n; i += 256) {
      int2 ed = ebuf[lo + i];
      int r = atomicAdd(&cnt[ed.y & 255], 1);
      eidx[lo + r] = ed.x;
    }
  }
}

// ---------------- weight pack (device fn, folded into k_fused preamble) ------
// frag idx t = (kb*NCT+ct)*64+lane holds B[kb*32+(lane>>4)*8+j][ct*16+(lane&15)]

__device__ __forceinline__ void pack_one(const float* __restrict__ W1,
                                         const float* __restrict__ W2,
                                         const float* __restrict__ Wout,
                                         _Float16* __restrict__ wp, int y, int t) {
  const float* W;
  _Float16* dstp;
  int NCT;
  if (y < 3) { W = W1 + (size_t)y * 16384; dstp = wp + y * 16384; NCT = 8; }
  else if (y < 6) { W = W2 + (size_t)(y - 3) * 16384; dstp = wp + 49152 + (y - 3) * 16384; NCT = 8; }
  else { W = Wout; dstp = wp + 98304; NCT = 4; }
  if (t >= 4 * NCT * 64) return;
  int lane = t & 63;
  int ct = (t >> 6) % NCT;
  int kb = t / (64 * NCT);
  int n = ct * 16 + (lane & 15);
  int k0 = kb * 32 + (lane >> 4) * 8;
  int N = NCT * 16;
#pragma unroll
  for (int j = 0; j < 8; ++j) dstp[t * 8 + j] = (_Float16)W[(k0 + j) * N + n];
}

// ---------------- software grid barrier ----------------
// Plain launch + manual barrier. Co-residency is guaranteed by arithmetic:
// __launch_bounds__(256,4) -> VGPR<=128 -> 4 blocks/CU; LDS 21.5KB -> 7/CU;
// waves 16/CU <= 32. Capacity 4*256=1024 >= 782 blocks, so every block is
// resident and the spin cannot deadlock. Thread 0 spins; fences give
// agent-scope release/acquire across non-coherent XCD L2s.

__device__ __forceinline__ void grid_barrier(int* bar, int idx) {
  __syncthreads();
  if (threadIdx.x == 0) {
    __threadfence();  // release prior writes (agent scope)
    __hip_atomic_fetch_add(bar + idx, 1, __ATOMIC_ACQ_REL, __HIP_MEMORY_SCOPE_AGENT);
    while (__hip_atomic_load(bar + idx, __ATOMIC_ACQUIRE, __HIP_MEMORY_SCOPE_AGENT) <
           NTILES) {
      __builtin_amdgcn_s_sleep(16);
    }
    __threadfence();  // acquire: invalidate stale cached lines
  }
  __syncthreads();
}

// ---------------- fused 3-layer GIN pipeline (persistent blocks) -------------
// One block per 64-node tile. Preamble: convert own tile fp32->fp16 (+ pack
// weights on blocks 0..55), barrier. Per layer: gather-agg -> LDS (z never in
// HBM), MFMA W1 -> x in LDS (never in HBM), stats atomics, barrier; BN+relu in
// LDS, MFMA W2, h' -> global (L<2) or LDS (L==2), barrier (L<2). Final: MFMA
// Wout from LDS, fp32 out.

__global__ __launch_bounds__(256, 4) void k_fused(
    const int* __restrict__ rs, const int* __restrict__ eidx,
    const float* __restrict__ eps, _Float16* __restrict__ h,
    _Float16* __restrict__ wp, const float* __restrict__ nf,
    const float* __restrict__ W1f, const float* __restrict__ W2f,
    const float* __restrict__ Woutf, const float* __restrict__ b1,
    const float* __restrict__ b2, const float* __restrict__ gamma,
    const float* __restrict__ beta, const float* __restrict__ bout,
    float* __restrict__ stats, int* __restrict__ bar, float* __restrict__ out) {
  __shared__ _Float16 As[64 * 136];  // 17408 B
  __shared__ float sredS[512];
  __shared__ float sredQ[512];

  const int tid = threadIdx.x;
  const int wid = tid >> 6;
  const int lane = tid & 63;
  const int slot = lane >> 4;  // quad
  const int c8 = lane & 15;
  const int c8t = tid & 15;
  const int rowBase = blockIdx.x * 64;
  const half8* wp8 = (const half8*)wp;

  // ---- preamble: convert own tile to fp16; blocks 0..55 also pack weights ----
#pragma unroll
  for (int ii = 0; ii < 4; ++ii) {
    int f = tid + ii * 256;
    int row = f >> 4;
    int gr = rowBase + row;
    int oct = f & 15;
    if (gr < NN) {
      const float4* x4 = (const float4*)(nf + (size_t)gr * 128 + oct * 8);
      float4 u = x4[0], v = x4[1];
      half8 o;
      o[0] = (_Float16)u.x; o[1] = (_Float16)u.y; o[2] = (_Float16)u.z; o[3] = (_Float16)u.w;
      o[4] = (_Float16)v.x; o[5] = (_Float16)v.y; o[6] = (_Float16)v.z; o[7] = (_Float16)v.w;
      *(half8*)(h + (size_t)gr * 128 + oct * 8) = o;
    }
  }
  if (blockIdx.x < 56)
    pack_one(W1f, W2f, Woutf, wp, blockIdx.x >> 3, ((blockIdx.x & 7) << 8) | tid);
  grid_barrier(bar, 0);

  for (int L = 0; L < 3; ++L) {
    const float ep = 1.0f + eps[L];
    const half8* h8 = (const half8*)h;

    // ---- phase A: aggregate this tile's 64 nodes into As ----
    for (int i = 0; i < 16; ++i) {
      const int node = rowBase + wid * 16 + i;
      float a0[8] = {0, 0, 0, 0, 0, 0, 0, 0};
      float a1[8] = {0, 0, 0, 0, 0, 0, 0, 0};
      float a2[8] = {0, 0, 0, 0, 0, 0, 0, 0};
      float a3[8] = {0, 0, 0, 0, 0, 0, 0, 0};
      int e0 = 0, e1 = 0;
      if (node < NN) {
        e0 = rs[node];
        e1 = rs[node + 1];
      }
      int e = e0 + slot;
      for (; e + 12 < e1; e += 16) {
        int s0 = eidx[e];
        int s1 = eidx[e + 4];
        int s2 = eidx[e + 8];
        int s3 = eidx[e + 12];
        half8 v0 = h8[s0 * 16 + c8];
        half8 v1 = h8[s1 * 16 + c8];
        half8 v2 = h8[s2 * 16 + c8];
        half8 v3 = h8[s3 * 16 + c8];
#pragma unroll
        for (int j = 0; j < 8; ++j) {
          a0[j] += (float)v0[j];
          a1[j] += (float)v1[j];
          a2[j] += (float)v2[j];
          a3[j] += (float)v3[j];
        }
      }
      for (; e < e1; e += 4) {
        half8 v = h8[eidx[e] * 16 + c8];
#pragma unroll
        for (int j = 0; j < 8; ++j) a0[j] += (float)v[j];
      }
#pragma unroll
      for (int j = 0; j < 8; ++j) {
        a0[j] += a1[j] + a2[j] + a3[j];
        a0[j] += __shfl_xor(a0[j], 16);
        a0[j] += __shfl_xor(a0[j], 32);
      }
      if (slot == 0) {
        half8 o = {0, 0, 0, 0, 0, 0, 0, 0};
        if (node < NN) {
          half8 hv = h8[node * 16 + c8];
#pragma unroll
          for (int j = 0; j < 8; ++j) o[j] = (_Float16)fmaf(ep, (float)hv[j], a0[j]);
        }
        *(half8*)(As + (wid * 16 + i) * 136 + c8 * 8) = o;
      }
    }
    __syncthreads();

    // ---- GEMM1: x = z @ W1 + b1 -> LDS, + stats ----
    floatx4 acc[8];
#pragma unroll
    for (int ct = 0; ct < 8; ++ct) acc[ct] = (floatx4){0.f, 0.f, 0.f, 0.f};
    const half8* w1 = wp8 + (size_t)L * 2048;
#pragma unroll
    for (int kb = 0; kb < 4; ++kb) {
      half8 a = *(const half8*)(As + (wid * 16 + c8) * 136 + kb * 32 + slot * 8);
#pragma unroll
      for (int ct = 0; ct < 8; ++ct)
        acc[ct] = __builtin_amdgcn_mfma_f32_16x16x32_f16(a, w1[(kb * 8 + ct) * 64 + lane],
                                                         acc[ct], 0, 0, 0);
    }
    float* csum = stats + L * 256;
    float* csq = csum + 128;
    const float* b1L = b1 + L * 128;
#pragma unroll
    for (int ct = 0; ct < 8; ++ct) {
      float bv = b1L[ct * 16 + c8];
      float ps = 0.f, pq = 0.f;
#pragma unroll
      for (int reg = 0; reg < 4; ++reg) {
        int row = wid * 16 + slot * 4 + reg;
        float x = acc[ct][reg] + bv;
        As[row * 136 + ct * 16 + c8] = (_Float16)x;  // own-wave rows only
        if (rowBase + row < NN) {
          ps += x;
          pq += x * x;
        }
      }
      ps += __shfl_xor(ps, 16);
      ps += __shfl_xor(ps, 32);
      pq += __shfl_xor(pq, 16);
      pq += __shfl_xor(pq, 32);
      if (lane < 16) {
        sredS[wid * 128 + ct * 16 + lane] = ps;
        sredQ[wid * 128 + ct * 16 + lane] = pq;
      }
    }
    __syncthreads();
    if (tid < 128) {
      float s = sredS[tid] + sredS[128 + tid] + sredS[256 + tid] + sredS[384 + tid];
      atomicAdd(&csum[tid], s);
    } else {
      int c = tid - 128;
      float q = sredQ[c] + sredQ[128 + c] + sredQ[256 + c] + sredQ[384 + c];
      atomicAdd(&csq[c], q);
    }
    grid_barrier(bar, 1 + 2 * L);

    // ---- phase B: BN + relu (LDS), GEMM2, h' out ----
    float sc[8], sh[8];
    {
      const float invM = 1.0f / (float)NN;
      const float* gL = gamma + L * 128;
      const float* bL = beta + L * 128;
#pragma unroll
      for (int j = 0; j < 8; ++j) {
        int k = c8t * 8 + j;
        float mu = csum[k] * invM;
        float var = csq[k] * invM - mu * mu;
        float g = gL[k] * rsqrtf(var + 1e-5f);
        sc[j] = g;
        sh[j] = fmaf(-mu, g, bL[k]);
      }
    }
#pragma unroll
    for (int ii = 0; ii < 4; ++ii) {
      int row = (tid + ii * 256) >> 4;
      half8 v = *(half8*)(As + row * 136 + c8t * 8);
#pragma unroll
      for (int j = 0; j < 8; ++j)
        v[j] = (_Float16)fmaxf(fmaf((float)v[j], sc[j], sh[j]), 0.f);
      *(half8*)(As + row * 136 + c8t * 8) = v;
    }
    __syncthreads();

    floatx4 acc2[8];
#pragma unroll
    for (int ct = 0; ct < 8; ++ct) acc2[ct] = (floatx4){0.f, 0.f, 0.f, 0.f};
    const half8* w2 = wp8 + 6144 + (size_t)L * 2048;
#pragma unroll
    for (int kb = 0; kb < 4; ++kb) {
      half8 a = *(const half8*)(As + (wid * 16 + c8) * 136 + kb * 32 + slot * 8);
#pragma unroll
      for (int ct = 0; ct < 8; ++ct)
        acc2[ct] = __builtin_amdgcn_mfma_f32_16x16x32_f16(a, w2[(kb * 8 + ct) * 64 + lane],
                                                          acc2[ct], 0, 0, 0);
    }
    const float* b2L = b2 + L * 128;
#pragma unroll
    for (int ct = 0; ct < 8; ++ct) {
      float bv = b2L[ct * 16 + c8];
#pragma unroll
      for (int reg = 0; reg < 4; ++reg) {
        int row = wid * 16 + slot * 4 + reg;
        float x = fmaxf(acc2[ct][reg] + bv, 0.f);
        As[row * 136 + ct * 16 + c8] = (_Float16)x;  // own-wave rows only
      }
    }
    __syncthreads();
    if (L < 2) {
#pragma unroll
      for (int ii = 0; ii < 4; ++ii) {
        int row = (tid + ii * 256) >> 4;
        int gr = rowBase + row;
        if (gr < NN) {
          half8 v = *(half8*)(As + row * 136 + c8t * 8);
          *(half8*)(h + (size_t)gr * 128 + c8t * 8) = v;
        }
      }
      grid_barrier(bar, 2 + 2 * L);
    }
  }

  // ---- final: out = h3 @ Wout + bout (h3 lives in As) ----
  floatx4 acc3[4];
#pragma unroll
  for (int ct = 0; ct < 4; ++ct) acc3[ct] = (floatx4){0.f, 0.f, 0.f, 0.f};
  const half8* wo = wp8 + 12288;
#pragma unroll
  for (int kb = 0; kb < 4; ++kb) {
    half8 a = *(const half8*)(As + (wid * 16 + c8) * 136 + kb * 32 + slot * 8);
#pragma unroll
    for (int ct = 0; ct < 4; ++ct)
      acc3[ct] = __builtin_amdgcn_mfma_f32_16x16x32_f16(a, wo[(kb * 4 + ct) * 64 + lane],
                                                        acc3[ct], 0, 0, 0);
  }
#pragma unroll
  for (int ct = 0; ct < 4; ++ct) {
    float bv = bout[ct * 16 + c8];
#pragma unroll
    for (int reg = 0; reg < 4; ++reg) {
      int gr = rowBase + wid * 16 + slot * 4 + reg;
      if (gr < NN) out[(size_t)gr * 64 + ct * 16 + c8] = acc3[ct][reg] + bv;
    }
  }
}

// ---------------- launch ----------------

extern "C" void kernel_launch(void* const* d_in, const int* in_sizes, int n_in,
                              void* d_out, int out_size, void* d_ws, size_t ws_size,
                              hipStream_t stream) {
  const float* node_feat = (const float*)d_in[0];
  const int* src = (const int*)d_in[1];
  const int* dst = (const int*)d_in[2];
  const float* W1 = (const float*)d_in[3];
  const float* b1 = (const float*)d_in[4];
  const float* gamma = (const float*)d_in[5];
  const float* beta = (const float*)d_in[6];
  const float* W2 = (const float*)d_in[7];
  const float* b2 = (const float*)d_in[8];
  const float* eps = (const float*)d_in[9];
  const float* Wout = (const float*)d_in[10];
  const float* bout = (const float*)d_in[11];
  float* out = (float*)d_out;

  // workspace layout (all 16B-aligned)
  int* rs = (int*)d_ws;               // 50176 ints
  int* gcnt = rs + 50176;             // 256
  int* bbase = gcnt + 256;            // 256
  int* bcur = bbase + 256;            // 256
  int* eidx = bcur + 256;             // NE ints
  _Float16* b0 = (_Float16*)(eidx + NE);   // h (6.4M halves)
  _Float16* wp = b0 + (size_t)NN * HID;    // packed weights (106496 halves)
  float* stats = (float*)(wp + 106496);    // 768 floats: 3 x (csum|csq)
  int* bar = (int*)(stats + 768);          // 8 ints: barrier counters
  int2* ebuf = (int2*)(bar + 8);           // NE int2 staging

  // CSR build
  hipMemsetAsync(gcnt, 0, NB * sizeof(int), stream);
  const int partGrid = (NE + 4095) / 4096;
  kb_count<<<partGrid, 256, 0, stream>>>(dst, gcnt, NE);
  kb_basescan<<<1, 256, 0, stream>>>(gcnt, bbase, bcur);
  kb_partition<<<partGrid, 256, 0, stream>>>(src, dst, bcur, ebuf, NE);
  kb_csr<<<NB, 256, 0, stream>>>(ebuf, bbase, rs, eidx, NN);

  hipMemsetAsync(stats, 0, 768 * sizeof(float) + 8 * sizeof(int), stream);

  k_fused<<<NTILES, 256, 0, stream>>>(rs, eidx, eps, b0, wp, node_feat, W1, W2,
                                      Wout, b1, b2, gamma, beta, bout, stats, bar,
                                      out);
}

// Round 10
// 450.682 us; speedup vs baseline: 3.2792x; 3.2792x over previous
//
#include <hip/hip_runtime.h>

#define NN 50000
#define NE 1600000
#define HID 128
#define NB 196      // dst buckets: dst>>8 -> 0..195 (256 nodes each)
#define BCAP 12288  // per-bucket LDS edge capacity

typedef _Float16 half8 __attribute__((ext_vector_type(8)));
typedef float floatx4 __attribute__((ext_vector_type(4)));

// ---------------- CSR build: two-level bucket sort (R5-verified) ----------------

__global__ __launch_bounds__(256) void kb_count(const int* __restrict__ dst,
                                                int* __restrict__ gcnt, int E) {
  __shared__ int cnt[NB];
  int tid = threadIdx.x;
  for (int i = tid; i < NB; i += 256) cnt[i] = 0;
  __syncthreads();
  int base = blockIdx.x * 4096;
  for (int i = 0; i < 16; ++i) {
    int e = base + i * 256 + tid;
    if (e < E) atomicAdd(&cnt[dst[e] >> 8], 1);
  }
  __syncthreads();
  for (int i = tid; i < NB; i += 256)
    if (cnt[i]) atomicAdd(&gcnt[i], cnt[i]);
}

__global__ __launch_bounds__(256) void kb_basescan(const int* __restrict__ gcnt,
                                                   int* __restrict__ bbase,
                                                   int* __restrict__ bcur) {
  __shared__ int s[256];
  int tid = threadIdx.x;
  int v = (tid < NB) ? gcnt[tid] : 0;
  s[tid] = v;
  __syncthreads();
  for (int d = 1; d < 256; d <<= 1) {
    int t = (tid >= d) ? s[tid - d] : 0;
    __syncthreads();
    s[tid] += t;
    __syncthreads();
  }
  int incl = s[tid];
  if (tid < NB) {
    bbase[tid] = incl - v;
    bcur[tid] = incl - v;
  }
  if (tid == NB - 1) bbase[NB] = incl;
}

__global__ __launch_bounds__(256) void kb_partition(const int* __restrict__ src,
                                                    const int* __restrict__ dst,
                                                    int* __restrict__ bcur,
                                                    int2* __restrict__ ebuf, int E) {
  __shared__ int cnt[NB];
  __shared__ int sbase[NB];
  int tid = threadIdx.x;
  for (int i = tid; i < NB; i += 256) cnt[i] = 0;
  __syncthreads();
  int base = blockIdx.x * 4096;
  int myd[16], mys[16];
#pragma unroll
  for (int i = 0; i < 16; ++i) {
    int e = base + i * 256 + tid;
    if (e < E) {
      myd[i] = dst[e];
      mys[i] = src[e];
      atomicAdd(&cnt[myd[i] >> 8], 1);
    } else {
      myd[i] = -1;
    }
  }
  __syncthreads();
  for (int i = tid; i < NB; i += 256)
    sbase[i] = cnt[i] ? atomicAdd(&bcur[i], cnt[i]) : 0;
  __syncthreads();
  for (int i = tid; i < NB; i += 256) cnt[i] = 0;
  __syncthreads();
#pragma unroll
  for (int i = 0; i < 16; ++i) {
    if (myd[i] >= 0) {
      int b = myd[i] >> 8;
      int r = atomicAdd(&cnt[b], 1);
      ebuf[sbase[b] + r] = make_int2(mys[i], myd[i]);
    }
  }
}

__global__ __launch_bounds__(256) void kb_csr(const int2* __restrict__ ebuf,
                                              const int* __restrict__ bbase,
                                              int* __restrict__ rs,
                                              int* __restrict__ eidx, int M) {
  __shared__ int cnt[256];
  __shared__ int off[256];
  __shared__ int sbuf[BCAP];
  int tid = threadIdx.x;
  int b = blockIdx.x;
  int lo = bbase[b], hi = bbase[b + 1];
  int n = hi - lo;
  cnt[tid] = 0;
  __syncthreads();
  for (int i = tid; i < n; i += 256) atomicAdd(&cnt[ebuf[lo + i].y & 255], 1);
  __syncthreads();
  int v = cnt[tid];
  off[tid] = v;
  __syncthreads();
  for (int d = 1; d < 256; d <<= 1) {
    int t = (tid >= d) ? off[tid - d] : 0;
    __syncthreads();
    off[tid] += t;
    __syncthreads();
  }
  int excl = off[tid] - v;
  int gnode = b * 256 + tid;
  if (gnode < M) rs[gnode] = lo + excl;
  if (b == NB - 1 && tid == 0) rs[M] = bbase[NB];
  __syncthreads();
  cnt[tid] = excl;
  __syncthreads();
  if (n <= BCAP) {
    for (int i = tid; i < n; i += 256) {
      int2 ed = ebuf[lo + i];
      int r = atomicAdd(&cnt[ed.y & 255], 1);
      sbuf[r] = ed.x;
    }
    __syncthreads();
    for (int i = tid; i < n; i += 256) eidx[lo + i] = sbuf[i];
  } else {
    for (int i = tid; i < n; i += 256) {
      int2 ed = ebuf[lo + i];
      int r = atomicAdd(&cnt[ed.y & 255], 1);
      eidx[lo + r] = ed.x;
    }
  }
}

// ---------------- fp32 -> fp16 convert (node_feat, once) ----------------

__global__ __launch_bounds__(256) void k_cvt(const float* __restrict__ x,
                                             _Float16* __restrict__ y, int n8) {
  int t = blockIdx.x * 256 + threadIdx.x;
  if (t >= n8) return;
  const float4* x4 = (const float4*)x;
  float4 u = x4[t * 2], v = x4[t * 2 + 1];
  half8 o;
  o[0] = (_Float16)u.x; o[1] = (_Float16)u.y; o[2] = (_Float16)u.z; o[3] = (_Float16)u.w;
  o[4] = (_Float16)v.x; o[5] = (_Float16)v.y; o[6] = (_Float16)v.z; o[7] = (_Float16)v.w;
  ((half8*)y)[t] = o;
}

// ---------------- weight pack: W[k][n] fp32 -> MFMA B-fragment order fp16 ----
// frag idx t = (kb*NCT+ct)*64+lane holds B[kb*32+(lane>>4)*8+j][ct*16+(lane&15)]

__global__ __launch_bounds__(256) void k_pack(const float* __restrict__ W1,
                                              const float* __restrict__ W2,
                                              const float* __restrict__ Wout,
                                              _Float16* __restrict__ wp) {
  int y = blockIdx.y;
  const float* W;
  _Float16* dst;
  int NCT;
  if (y < 3) { W = W1 + (size_t)y * 16384; dst = wp + y * 16384; NCT = 8; }
  else if (y < 6) { W = W2 + (size_t)(y - 3) * 16384; dst = wp + 49152 + (y - 3) * 16384; NCT = 8; }
  else { W = Wout; dst = wp + 98304; NCT = 4; }
  int t = blockIdx.x * 256 + threadIdx.x;
  if (t >= 4 * NCT * 64) return;
  int lane = t & 63;
  int ct = (t >> 6) % NCT;
  int kb = t / (64 * NCT);
  int n = ct * 16 + (lane & 15);
  int k0 = kb * 32 + (lane >> 4) * 8;
  int N = NCT * 16;
#pragma unroll
  for (int j = 0; j < 8; ++j) dst[t * 8 + j] = (_Float16)W[(k0 + j) * N + n];
}

// ---------------- fused agg + GEMM1 + stats ----------------
// 1024-thread blocks (16 waves), 64 nodes/block. Each wave aggregates 4 nodes
// (same 4-chain inner loop as R7's k_agg16) straight into LDS (z never in
// HBM), then wave w = rg + 4*cg computes rows rg*16..+15 x cols cg*32..+31 of
// x = z@W1+b1, writes x to global and accumulates BN stats.
// __launch_bounds__(1024,8): VGPR<=64 -> 2 blocks/CU = 32 waves/CU gather
// concurrency (R7 agg ran at 18). No grid barriers (R9: barrier fences cost
// ~180us each via per-block L2 invalidation).

__global__ __launch_bounds__(1024, 8) void k_aggemm1(
    const int* __restrict__ rs, const int* __restrict__ eidx,
    const float* __restrict__ eps, int layer, const _Float16* __restrict__ h,
    const _Float16* __restrict__ wp1, const float* __restrict__ b1L,
    float* __restrict__ csum, float* __restrict__ csq,
    _Float16* __restrict__ x) {
  __shared__ _Float16 As[64 * 136];
  __shared__ float sredS[512];
  __shared__ float sredQ[512];
  const int tid = threadIdx.x;
  const int wid = tid >> 6;
  const int lane = tid & 63;
  const int slot = lane >> 4;
  const int c8 = lane & 15;
  const int rowBase = blockIdx.x * 64;
  const float ep = 1.0f + eps[layer];
  const half8* h8 = (const half8*)h;

  // ---- aggregate: wave wid handles nodes rowBase + wid*4 + i ----
  for (int i = 0; i < 4; ++i) {
    const int node = rowBase + wid * 4 + i;
    float a0[8] = {0, 0, 0, 0, 0, 0, 0, 0};
    float a1[8] = {0, 0, 0, 0, 0, 0, 0, 0};
    float a2[8] = {0, 0, 0, 0, 0, 0, 0, 0};
    float a3[8] = {0, 0, 0, 0, 0, 0, 0, 0};
    int e0 = 0, e1 = 0;
    if (node < NN) {
      e0 = rs[node];
      e1 = rs[node + 1];
    }
    int e = e0 + slot;
    for (; e + 12 < e1; e += 16) {
      int s0 = eidx[e];
      int s1 = eidx[e + 4];
      int s2 = eidx[e + 8];
      int s3 = eidx[e + 12];
      half8 v0 = h8[s0 * 16 + c8];
      half8 v1 = h8[s1 * 16 + c8];
      half8 v2 = h8[s2 * 16 + c8];
      half8 v3 = h8[s3 * 16 + c8];
#pragma unroll
      for (int j = 0; j < 8; ++j) {
        a0[j] += (float)v0[j];
        a1[j] += (float)v1[j];
        a2[j] += (float)v2[j];
        a3[j] += (float)v3[j];
      }
    }
    for (; e < e1; e += 4) {
      half8 v = h8[eidx[e] * 16 + c8];
#pragma unroll
      for (int j = 0; j < 8; ++j) a0[j] += (float)v[j];
    }
#pragma unroll
    for (int j = 0; j < 8; ++j) {
      a0[j] += a1[j] + a2[j] + a3[j];
      a0[j] += __shfl_xor(a0[j], 16);
      a0[j] += __shfl_xor(a0[j], 32);
    }
    if (slot == 0) {
      half8 o = {0, 0, 0, 0, 0, 0, 0, 0};
      if (node < NN) {
        half8 hv = h8[node * 16 + c8];
#pragma unroll
        for (int j = 0; j < 8; ++j) o[j] = (_Float16)fmaf(ep, (float)hv[j], a0[j]);
      }
      *(half8*)(As + (wid * 4 + i) * 136 + c8 * 8) = o;
    }
  }
  __syncthreads();

  // ---- GEMM1: wave (rg,cg) does rows rg*16..+15, cols cg*32..+31 ----
  const int rg = wid & 3;
  const int cg = wid >> 2;
  floatx4 acc[2];
  acc[0] = (floatx4){0.f, 0.f, 0.f, 0.f};
  acc[1] = (floatx4){0.f, 0.f, 0.f, 0.f};
  const half8* wp8 = (const half8*)wp1;
#pragma unroll
  for (int kb = 0; kb < 4; ++kb) {
    half8 a = *(const half8*)(As + (rg * 16 + c8) * 136 + kb * 32 + slot * 8);
#pragma unroll
    for (int t = 0; t < 2; ++t) {
      int ct = cg * 2 + t;
      acc[t] = __builtin_amdgcn_mfma_f32_16x16x32_f16(a, wp8[(kb * 8 + ct) * 64 + lane],
                                                      acc[t], 0, 0, 0);
    }
  }
#pragma unroll
  for (int t = 0; t < 2; ++t) {
    int ct = cg * 2 + t;
    float bv = b1L[ct * 16 + c8];
    float ps = 0.f, pq = 0.f;
#pragma unroll
    for (int reg = 0; reg < 4; ++reg) {
      int row = rg * 16 + slot * 4 + reg;
      int gr = rowBase + row;
      float xv = acc[t][reg] + bv;
      if (gr < NN) {
        x[(size_t)gr * 128 + ct * 16 + c8] = (_Float16)xv;
        ps += xv;
        pq += xv * xv;
      }
    }
    ps += __shfl_xor(ps, 16);
    ps += __shfl_xor(ps, 32);
    pq += __shfl_xor(pq, 16);
    pq += __shfl_xor(pq, 32);
    if (lane < 16) {
      sredS[wid * 32 + t * 16 + lane] = ps;
      sredQ[wid * 32 + t * 16 + lane] = pq;
    }
  }
  __syncthreads();
  if (tid < 128) {
    int c = tid;
    int wbase = (c >> 5) * 4;
    int loc = c & 31;
    float s = sredS[wbase * 32 + loc] + sredS[(wbase + 1) * 32 + loc] +
              sredS[(wbase + 2) * 32 + loc] + sredS[(wbase + 3) * 32 + loc];
    atomicAdd(&csum[c], s);
  } else if (tid < 256) {
    int c = tid - 128;
    int wbase = (c >> 5) * 4;
    int loc = c & 31;
    float q = sredQ[wbase * 32 + loc] + sredQ[(wbase + 1) * 32 + loc] +
              sredQ[(wbase + 2) * 32 + loc] + sredQ[(wbase + 3) * 32 + loc];
    atomicAdd(&csq[c], q);
  }
}

// ---------------- BN + GEMM2 (+ final Wout GEMM when FINAL) ----------------
// 1024-thread blocks, 64 rows/block. Stage x with BN+relu into LDS, MFMA W2,
// h' -> global (FINAL=0) or keep h3 in LDS and chain Wout MFMA -> out (FINAL=1).

template <int FINAL>
__global__ __launch_bounds__(1024, 8) void k_bn_gemm2(
    const _Float16* __restrict__ x, const _Float16* __restrict__ wp2,
    const float* __restrict__ b2L, const float* __restrict__ gammaL,
    const float* __restrict__ betaL, const float* __restrict__ csum,
    const float* __restrict__ csq, _Float16* __restrict__ hout,
    const _Float16* __restrict__ wpo, const float* __restrict__ boutp,
    float* __restrict__ out) {
  __shared__ _Float16 As[64 * 136];
  const int tid = threadIdx.x;
  const int wid = tid >> 6;
  const int lane = tid & 63;
  const int slot = lane >> 4;
  const int c8 = lane & 15;
  const int c8t = tid & 15;
  const int rowBase = blockIdx.x * 64;

  // BN coefficients for this thread's staged octet
  float sc[8], sh[8];
  {
    const float invM = 1.0f / (float)NN;
#pragma unroll
    for (int j = 0; j < 8; ++j) {
      int k = c8t * 8 + j;
      float mu = csum[k] * invM;
      float var = csq[k] * invM - mu * mu;
      float g = gammaL[k] * rsqrtf(var + 1e-5f);
      sc[j] = g;
      sh[j] = fmaf(-mu, g, betaL[k]);
    }
  }
  // stage x with BN+relu (1024 threads x one half8 = 64 rows x 128)
  {
    int row = tid >> 4;
    int gr = rowBase + row;
    half8 v = {0, 0, 0, 0, 0, 0, 0, 0};
    if (gr < NN) {
      v = *(const half8*)(x + (size_t)gr * 128 + c8t * 8);
#pragma unroll
      for (int j = 0; j < 8; ++j)
        v[j] = (_Float16)fmaxf(fmaf((float)v[j], sc[j], sh[j]), 0.f);
    }
    *(half8*)(As + row * 136 + c8t * 8) = v;
  }
  __syncthreads();

  const int rg = wid & 3;
  const int cg = wid >> 2;
  floatx4 acc[2];
  acc[0] = (floatx4){0.f, 0.f, 0.f, 0.f};
  acc[1] = (floatx4){0.f, 0.f, 0.f, 0.f};
  const half8* wp8 = (const half8*)wp2;
#pragma unroll
  for (int kb = 0; kb < 4; ++kb) {
    half8 a = *(const half8*)(As + (rg * 16 + c8) * 136 + kb * 32 + slot * 8);
#pragma unroll
    for (int t = 0; t < 2; ++t) {
      int ct = cg * 2 + t;
      acc[t] = __builtin_amdgcn_mfma_f32_16x16x32_f16(a, wp8[(kb * 8 + ct) * 64 + lane],
                                                      acc[t], 0, 0, 0);
    }
  }
  __syncthreads();  // all waves done reading As before overwrite
  // h' = relu(acc + b2) -> LDS
#pragma unroll
  for (int t = 0; t < 2; ++t) {
    int ct = cg * 2 + t;
    float bv = b2L[ct * 16 + c8];
#pragma unroll
    for (int reg = 0; reg < 4; ++reg) {
      int row = rg * 16 + slot * 4 + reg;
      As[row * 136 + ct * 16 + c8] = (_Float16)fmaxf(acc[t][reg] + bv, 0.f);
    }
  }
  __syncthreads();

  if (FINAL == 0) {
    int row = tid >> 4;
    int gr = rowBase + row;
    if (gr < NN) {
      half8 v = *(half8*)(As + row * 136 + c8t * 8);
      *(half8*)(hout + (size_t)gr * 128 + c8t * 8) = v;
    }
  } else {
    // out = h3 @ Wout + bout; waves with cg<2 cover cols 0..63
    if (cg < 2) {
      floatx4 acc3[2];
      acc3[0] = (floatx4){0.f, 0.f, 0.f, 0.f};
      acc3[1] = (floatx4){0.f, 0.f, 0.f, 0.f};
      const half8* wo8 = (const half8*)wpo;
#pragma unroll
      for (int kb = 0; kb < 4; ++kb) {
        half8 a = *(const half8*)(As + (rg * 16 + c8) * 136 + kb * 32 + slot * 8);
#pragma unroll
        for (int t = 0; t < 2; ++t) {
          int ct = cg * 2 + t;
          acc3[t] = __builtin_amdgcn_mfma_f32_16x16x32_f16(
              a, wo8[(kb * 4 + ct) * 64 + lane], acc3[t], 0, 0, 0);
        }
      }
#pragma unroll
      for (int t = 0; t < 2; ++t) {
        int ct = cg * 2 + t;
        float bv = boutp[ct * 16 + c8];
#pragma unroll
        for (int reg = 0; reg < 4; ++reg) {
          int gr = rowBase + rg * 16 + slot * 4 + reg;
          if (gr < NN) out[(size_t)gr * 64 + ct * 16 + c8] = acc3[t][reg] + bv;
        }
      }
    }
  }
}

// ---------------- launch ----------------

extern "C" void kernel_launch(void* const* d_in, const int* in_sizes, int n_in,
                              void* d_out, int out_size, void* d_ws, size_t ws_size,
                              hipStream_t stream) {
  const float* node_feat = (const float*)d_in[0];
  const int* src = (const int*)d_in[1];
  const int* dst = (const int*)d_in[2];
  const float* W1 = (const float*)d_in[3];
  const float* b1 = (const float*)d_in[4];
  const float* gamma = (const float*)d_in[5];
  const float* beta = (const float*)d_in[6];
  const float* W2 = (const float*)d_in[7];
  const float* b2 = (const float*)d_in[8];
  const float* eps = (const float*)d_in[9];
  const float* Wout = (const float*)d_in[10];
  const float* bout = (const float*)d_in[11];
  float* out = (float*)d_out;

  // workspace layout (16B-aligned slices)
  int* rs = (int*)d_ws;                  // 50176 ints
  int* gcnt = rs + 50176;                // 256
  int* bbase = gcnt + 256;               // 256
  int* bcur = bbase + 256;               // 256
  float* stats = (float*)(bcur + 256);   // 768 floats: 3 x (csum|csq)
  int* eidx = (int*)(stats + 768);       // NE ints
  _Float16* hb = (_Float16*)(eidx + NE);      // h  (6.4M halves)
  _Float16* xb = hb + (size_t)NN * HID;       // x  (6.4M halves)
  _Float16* wp = xb + (size_t)NN * HID;       // packed weights (106496 halves)
  int2* ebuf = (int2*)(wp + 106496);          // NE int2 staging

  // single memset: gcnt + bbase + bcur + stats (bbase/bcur rewritten anyway)
  hipMemsetAsync(gcnt, 0, (256 * 3 + 768) * sizeof(int), stream);

  k_cvt<<<(NN * HID / 8 + 255) / 256, 256, 0, stream>>>(node_feat, hb, NN * HID / 8);
  k_pack<<<dim3(8, 7), 256, 0, stream>>>(W1, W2, Wout, wp);

  const int partGrid = (NE + 4095) / 4096;
  kb_count<<<partGrid, 256, 0, stream>>>(dst, gcnt, NE);
  kb_basescan<<<1, 256, 0, stream>>>(gcnt, bbase, bcur);
  kb_partition<<<partGrid, 256, 0, stream>>>(src, dst, bcur, ebuf, NE);
  kb_csr<<<NB, 256, 0, stream>>>(ebuf, bbase, rs, eidx, NN);

  const int rowTiles = (NN + 63) / 64;  // 782

  for (int L = 0; L < 3; ++L) {
    float* csum = stats + L * 256;
    float* csq = csum + 128;
    k_aggemm1<<<rowTiles, 1024, 0, stream>>>(
        rs, eidx, eps, L, hb, wp + (size_t)L * 16384, b1 + (size_t)L * HID,
        csum, csq, xb);
    if (L < 2) {
      k_bn_gemm2<0><<<rowTiles, 1024, 0, stream>>>(
          xb, wp + 49152 + (size_t)L * 16384, b2 + (size_t)L * HID,
          gamma + (size_t)L * HID, beta + (size_t)L * HID, csum, csq, hb,
          nullptr, nullptr, nullptr);
    } else {
      k_bn_gemm2<1><<<rowTiles, 1024, 0, stream>>>(
          xb, wp + 49152 + (size_t)L * 16384, b2 + (size_t)L * HID,
          gamma + (size_t)L * HID, beta + (size_t)L * HID, csum, csq, nullptr,
          wp + 98304, bout, out);
    }
  }
}